// Round 5
// baseline (297.909 us; speedup 1.0000x reference)
//
#include <hip/hip_runtime.h>

// GridPoolingLayer: per-cell mean pooling; cells are rectangles from rising
// edges of h_mask/v_mask. H=W=768, C=64, fp32.
//
// R5: FUSED single-pass. Column segments are greedily packed into tiles of
// width <= 64 px aligned to segment boundaries, so every cell is wholly
// owned by one (row_seg, tile) block. Block: register colsum over strip
// rows (coalesced 1KB/wave) -> per-cell means in LDS -> broadcast out.
// Read input once + write output once; no intermediate global traffic.
// If any col segment is wider than 64 (data-dependent, ~impossible here),
// ws[OFF_FB]=1 routes all work to the R2-style fallback kernel instead.

#define GH 768
#define GW 768
#define MAXSEG 385       // alternating mask: 384 rising edges -> 385 segments
#define ROWQ (GW * 16)   // float4 per image row
#define TILEW 64         // max tile width in pixels
#define MAXT 26          // max tiles (pairs of adjacent tiles sum > 64 -> <=24)

enum {
    OFF_ROWSTART = 0,
    OFF_ROWEND   = OFF_ROWSTART + MAXSEG,
    OFF_COLSTART = OFF_ROWEND + MAXSEG,
    OFF_COLEND   = OFF_COLSTART + MAXSEG,
    OFF_NROWS    = OFF_COLEND + MAXSEG,
    OFF_NCOLS,
    OFF_NTILES,
    OFF_FB,
    OFF_CID,                       // 768 per-pixel col segment ids
    OFF_TX0 = OFF_CID + GW,        // tile x start
    OFF_TX1 = OFF_TX0 + MAXT,      // tile x end
    OFF_TFS = OFF_TX1 + MAXT,      // tile first segment index
    OFF_END = OFF_TFS + MAXT,
};

__device__ __forceinline__ void acc4(float4& a, const float4 v) {
    a.x += v.x; a.y += v.y; a.z += v.z; a.w += v.w;
}

__global__ __launch_bounds__(768) void seg_scan(const int* __restrict__ h_mask,
                                                const int* __restrict__ v_mask,
                                                int* __restrict__ ws) {
    __shared__ int s[GH];
    __shared__ int lstart[MAXSEG], lend[MAXSEG];
    const int i = threadIdx.x;
    const bool is_row = (blockIdx.x == 0);
    const int* m = is_row ? h_mask : v_mask;

    int rising = 0;
    if (i > 0) rising = (m[i] == 1 && m[i - 1] == 0) ? 1 : 0;  // rising[0] forced 0
    s[i] = rising;
    __syncthreads();

    for (int off = 1; off < GH; off <<= 1) {
        int add = (i >= off) ? s[i - off] : 0;
        __syncthreads();
        s[i] += add;
        __syncthreads();
    }

    const int seg  = s[i];
    const int segL = (i == 0)      ? -1 : s[i - 1];
    const int segR = (i == GH - 1) ? -2 : s[i + 1];

    int* start = ws + (is_row ? OFF_ROWSTART : OFF_COLSTART);
    int* end   = ws + (is_row ? OFF_ROWEND   : OFF_COLEND);
    if (seg != segL) { start[seg] = i;     if (!is_row) lstart[seg] = i; }
    if (seg != segR) { end[seg]   = i + 1; if (!is_row) lend[seg] = i + 1; }
    if (i == GH - 1) ws[is_row ? OFF_NROWS : OFF_NCOLS] = seg + 1;

    if (!is_row) {
        ws[OFF_CID + i] = seg;
        __syncthreads();   // col block only: make lstart/lend visible
        if (i == 0) {
            const int nseg = s[GH - 1] + 1;
            int fb = 0, t = 0, first = 0, curw = 0;
            for (int sg = 0; sg < nseg; ++sg) {
                const int w = lend[sg] - lstart[sg];
                if (w > TILEW) fb = 1;
                if (curw > 0 && curw + w > TILEW) {
                    if (t < MAXT) {
                        ws[OFF_TX0 + t] = lstart[first];
                        ws[OFF_TX1 + t] = lend[sg - 1];
                        ws[OFF_TFS + t] = first;
                    }
                    ++t; first = sg; curw = 0;
                }
                curw += w;
            }
            if (t < MAXT) {
                ws[OFF_TX0 + t] = lstart[first];
                ws[OFF_TX1 + t] = lend[nseg - 1];
                ws[OFF_TFS + t] = first;
            }
            ++t;
            if (t > MAXT) fb = 1;
            ws[OFF_NTILES] = (t <= MAXT) ? t : 0;
            ws[OFF_FB] = fb;
        }
    }
}

// ---- Fused: one block per (row segment, col tile) ----
__global__ __launch_bounds__(256) void strip_pool(const float4* __restrict__ in,
                                                  float4* __restrict__ out,
                                                  const int* __restrict__ ws) {
    if (ws[OFF_FB]) return;
    const int r = blockIdx.y;
    const int t = blockIdx.x;
    if (r >= ws[OFF_NROWS] || t >= ws[OFF_NTILES]) return;

    const int y0  = ws[OFF_ROWSTART + r];
    const int y1  = ws[OFF_ROWEND + r];
    const int tx0 = ws[OFF_TX0 + t];
    const int tx1 = ws[OFF_TX1 + t];
    const int tfs = ws[OFF_TFS + t];
    const int nu  = (tx1 - tx0) * 16;   // float4 slots in tile row, <= 1024
    const int tid = threadIdx.x;
    const int u0 = tid, u1 = tid + 256, u2 = tid + 512, u3 = tid + 768;

    float4 a0 = make_float4(0.f,0.f,0.f,0.f), a1 = a0, a2 = a0, a3 = a0;
    for (int y = y0; y < y1; ++y) {
        const float4* rp = in + (size_t)y * ROWQ + (size_t)tx0 * 16;
        if (u0 < nu) acc4(a0, rp[u0]);
        if (u1 < nu) acc4(a1, rp[u1]);
        if (u2 < nu) acc4(a2, rp[u2]);
        if (u3 < nu) acc4(a3, rp[u3]);
    }

    __shared__ float4 colsum[TILEW * 16];   // 16 KB
    __shared__ float4 means[TILEW * 16];    // 16 KB
    if (u0 < nu) colsum[u0] = a0;
    if (u1 < nu) colsum[u1] = a1;
    if (u2 < nu) colsum[u2] = a2;
    if (u3 < nu) colsum[u3] = a3;
    __syncthreads();

    const int nst = ws[OFF_CID + tx1 - 1] - tfs + 1;  // segments in tile
    const float hh = (float)(y1 - y0);
    for (int v = tid; v < nst * 16; v += 256) {
        const int sl = v >> 4, cq = v & 15;
        const int gx0 = ws[OFF_COLSTART + tfs + sl] - tx0;
        const int gx1 = ws[OFF_COLEND + tfs + sl] - tx0;
        float4 a = make_float4(0.f,0.f,0.f,0.f);
        for (int x = gx0; x < gx1; ++x) acc4(a, colsum[x * 16 + cq]);
        const float area = hh * (float)(gx1 - gx0);   // >= 1 always
        means[v] = make_float4(a.x / area, a.y / area, a.z / area, a.w / area);
    }
    __syncthreads();

    float4 m0, m1, m2, m3;
    if (u0 < nu) m0 = means[(ws[OFF_CID + tx0 + (u0 >> 4)] - tfs) * 16 + (u0 & 15)];
    if (u1 < nu) m1 = means[(ws[OFF_CID + tx0 + (u1 >> 4)] - tfs) * 16 + (u1 & 15)];
    if (u2 < nu) m2 = means[(ws[OFF_CID + tx0 + (u2 >> 4)] - tfs) * 16 + (u2 & 15)];
    if (u3 < nu) m3 = means[(ws[OFF_CID + tx0 + (u3 >> 4)] - tfs) * 16 + (u3 & 15)];
    for (int y = y0; y < y1; ++y) {
        float4* op = out + (size_t)y * ROWQ + (size_t)tx0 * 16;
        if (u0 < nu) op[u0] = m0;
        if (u1 < nu) op[u1] = m1;
        if (u2 < nu) op[u2] = m2;
        if (u3 < nu) op[u3] = m3;
    }
}

// ---- Fallback (runs only when a col segment is wider than TILEW) ----
__global__ __launch_bounds__(256) void cell_pool(const float4* __restrict__ in,
                                                 float4* __restrict__ out,
                                                 const int* __restrict__ ws) {
    if (ws[OFF_FB] == 0) return;
    const int nrows  = ws[OFF_NROWS];
    const int ncols  = ws[OFF_NCOLS];
    const int ncells = nrows * ncols;

    const int wave   = blockIdx.x * 4 + (threadIdx.x >> 6);
    const int nwaves = gridDim.x * 4;
    const int lane   = threadIdx.x & 63;
    const int pg     = lane >> 4;
    const int cq     = lane & 15;

    for (int cell = wave; cell < ncells; cell += nwaves) {
        const int br = cell / ncols;
        const int bc = cell - br * ncols;
        const int y0 = ws[OFF_ROWSTART + br];
        const int y1 = ws[OFF_ROWEND + br];
        const int x0 = ws[OFF_COLSTART + bc];
        const int x1 = ws[OFF_COLEND + bc];

        float4 a = make_float4(0.f,0.f,0.f,0.f);
        for (int y = y0; y < y1; ++y) {
            const size_t rb = (size_t)y * ROWQ + cq;
            for (int x = x0 + pg; x < x1; x += 4)
                acc4(a, in[rb + (size_t)x * 16]);
        }
        #pragma unroll
        for (int msk = 16; msk < 64; msk <<= 1) {
            a.x += __shfl_xor(a.x, msk, 64);
            a.y += __shfl_xor(a.y, msk, 64);
            a.z += __shfl_xor(a.z, msk, 64);
            a.w += __shfl_xor(a.w, msk, 64);
        }
        const float area = (float)((y1 - y0) * (x1 - x0));
        float4 mn = make_float4(a.x / area, a.y / area, a.z / area, a.w / area);
        for (int y = y0; y < y1; ++y) {
            const size_t rb = (size_t)y * ROWQ + cq;
            for (int x = x0 + pg; x < x1; x += 4)
                out[rb + (size_t)x * 16] = mn;
        }
    }
}

extern "C" void kernel_launch(void* const* d_in, const int* in_sizes, int n_in,
                              void* d_out, int out_size, void* d_ws, size_t ws_size,
                              hipStream_t stream) {
    const float* in  = (const float*)d_in[0];   // [1,768,768,64] fp32
    const int* hmask = (const int*)d_in[1];     // [1,768] int32
    const int* vmask = (const int*)d_in[2];     // [1,768] int32
    float* out = (float*)d_out;                 // [1,768,768,64] fp32
    int* ws = (int*)d_ws;

    seg_scan<<<2, GH, 0, stream>>>(hmask, vmask, ws);
    dim3 grid(MAXT, MAXSEG);   // (tile, row segment); extras early-exit
    strip_pool<<<grid, 256, 0, stream>>>((const float4*)in, (float4*)out, ws);
    cell_pool<<<2048, 256, 0, stream>>>((const float4*)in, (float4*)out, ws);
}

// Round 6
// 297.349 us; speedup vs baseline: 1.0019x; 1.0019x over previous
//
#include <hip/hip_runtime.h>

// GridPoolingLayer: per-cell mean pooling; cells are rectangles from rising
// edges of h_mask/v_mask. H=W=768, C=64, fp32.
//
// R6: separable 3-phase pipeline, every phase uniform-granularity:
//   col_sum  : grid-stride over (row_seg, x, chquad); wave-uniform height,
//              4-deep unrolled accumulators. -> colsum in d_ws (<=75.7MB).
//   cell_mean: grid-stride over (row_seg, col_seg, chquad); sum colsum over
//              the col segment / area. -> means in d_ws (<=38MB).
//   bcast    : ONE BLOCK PER IMAGE ROW (768 blocks = 3/CU, uniform cost),
//              48 coalesced float4 stores per thread, cid map in LDS,
//              means gathered via L2. Pure streaming write.
// No atomics, no queues, no per-cell blocks. R2-style static fallback only
// if ws_size can't hold the intermediates.

#define GH 768
#define GW 768
#define MAXSEG 385       // alternating mask: 384 rising edges -> 385 segments
#define ROWQ (GW * 16)   // float4 per image row = 12288

enum {
    OFF_ROWSTART = 0,
    OFF_ROWEND   = OFF_ROWSTART + MAXSEG,
    OFF_COLSTART = OFF_ROWEND + MAXSEG,
    OFF_COLEND   = OFF_COLSTART + MAXSEG,
    OFF_NROWS    = OFF_COLEND + MAXSEG,
    OFF_NCOLS,
    OFF_RID,                        // 768 per-pixel row segment ids
    OFF_CID = OFF_RID + GH,         // 768 per-pixel col segment ids
    OFF_END = OFF_CID + GW,
};

#define COLSUM_OFF_BYTES  16384
#define COLSUM_CAP_BYTES  ((size_t)MAXSEG * ROWQ * 16)          // 75.7 MB
#define MEANS_OFF_BYTES   (COLSUM_OFF_BYTES + COLSUM_CAP_BYTES)
#define MEANS_CAP_BYTES   ((size_t)MAXSEG * MAXSEG * 16 * 16)   // 37.9 MB
#define WS_NEED_BYTES     (MEANS_OFF_BYTES + MEANS_CAP_BYTES)

__device__ __forceinline__ void acc4(float4& a, const float4 v) {
    a.x += v.x; a.y += v.y; a.z += v.z; a.w += v.w;
}

__global__ __launch_bounds__(768) void seg_scan(const int* __restrict__ h_mask,
                                                const int* __restrict__ v_mask,
                                                int* __restrict__ ws) {
    __shared__ int s[GH];
    const int i = threadIdx.x;
    const bool is_row = (blockIdx.x == 0);
    const int* m = is_row ? h_mask : v_mask;

    int rising = 0;
    if (i > 0) rising = (m[i] == 1 && m[i - 1] == 0) ? 1 : 0;  // rising[0] forced 0
    s[i] = rising;
    __syncthreads();

    for (int off = 1; off < GH; off <<= 1) {
        int add = (i >= off) ? s[i - off] : 0;
        __syncthreads();
        s[i] += add;
        __syncthreads();
    }

    const int seg  = s[i];
    const int segL = (i == 0)      ? -1 : s[i - 1];
    const int segR = (i == GH - 1) ? -2 : s[i + 1];

    int* start = ws + (is_row ? OFF_ROWSTART : OFF_COLSTART);
    int* end   = ws + (is_row ? OFF_ROWEND   : OFF_COLEND);
    if (seg != segL) start[seg] = i;
    if (seg != segR) end[seg]   = i + 1;
    ws[(is_row ? OFF_RID : OFF_CID) + i] = seg;
    if (i == GH - 1) ws[is_row ? OFF_NROWS : OFF_NCOLS] = seg + 1;
}

// ---- Phase A: colsum[r][x][cq] = sum_{y in rowseg r} in[y][x][cq] ----
__global__ __launch_bounds__(256) void col_sum(const float4* __restrict__ in,
                                               float4* __restrict__ colsum,
                                               const int* __restrict__ ws) {
    const int N = ws[OFF_NROWS] * ROWQ;
    const int stride = gridDim.x * blockDim.x;   // multiple of 64
    for (int u = blockIdx.x * blockDim.x + threadIdx.x; u < N; u += stride) {
        const int r   = u / ROWQ;                // wave-uniform (ROWQ % 64 == 0)
        const int rem = u - r * ROWQ;
        const int y0 = ws[OFF_ROWSTART + r];
        const int y1 = ws[OFF_ROWEND + r];
        float4 a0 = make_float4(0.f,0.f,0.f,0.f), a1 = a0, a2 = a0, a3 = a0;
        int y = y0;
        for (; y + 3 < y1; y += 4) {
            acc4(a0, in[(size_t)y * ROWQ + rem]);
            acc4(a1, in[(size_t)(y + 1) * ROWQ + rem]);
            acc4(a2, in[(size_t)(y + 2) * ROWQ + rem]);
            acc4(a3, in[(size_t)(y + 3) * ROWQ + rem]);
        }
        for (; y < y1; ++y) acc4(a0, in[(size_t)y * ROWQ + rem]);
        acc4(a0, a1); acc4(a2, a3); acc4(a0, a2);
        colsum[u] = a0;
    }
}

// ---- Phase B: means[r][s][cq] = (sum_{x in colseg s} colsum[r][x][cq])/area ----
__global__ __launch_bounds__(256) void cell_mean(const float4* __restrict__ colsum,
                                                 float4* __restrict__ means,
                                                 const int* __restrict__ ws) {
    const int nrows = ws[OFF_NROWS];
    const int ncols = ws[OFF_NCOLS];
    const int N = nrows * ncols * 16;
    const int stride = gridDim.x * blockDim.x;
    for (int v = blockIdx.x * blockDim.x + threadIdx.x; v < N; v += stride) {
        const int cq = v & 15;
        const int rs = v >> 4;
        const int r  = rs / ncols;
        const int s  = rs - r * ncols;
        const int x0 = ws[OFF_COLSTART + s];
        const int x1 = ws[OFF_COLEND + s];
        float4 a = make_float4(0.f,0.f,0.f,0.f);
        for (int x = x0; x < x1; ++x)
            acc4(a, colsum[(size_t)r * ROWQ + x * 16 + cq]);
        const float area =
            (float)((ws[OFF_ROWEND + r] - ws[OFF_ROWSTART + r]) * (x1 - x0));
        means[v] = make_float4(a.x / area, a.y / area, a.z / area, a.w / area);
    }
}

// ---- Phase C: one block per image row; out[y][x][cq] = means[rid[y]][cid[x]][cq] ----
__global__ __launch_bounds__(256) void bcast(const float4* __restrict__ means,
                                             float4* __restrict__ out,
                                             const int* __restrict__ ws) {
    __shared__ int scid[GW];
    const int y   = blockIdx.x;
    const int tid = threadIdx.x;
    for (int x = tid; x < GW; x += 256) scid[x] = ws[OFF_CID + x];
    const int rid   = ws[OFF_RID + y];
    const int ncols = ws[OFF_NCOLS];
    const size_t mrow = (size_t)rid * ncols * 16;
    __syncthreads();

    float4* orow = out + (size_t)y * ROWQ;
    #pragma unroll 4
    for (int u = tid; u < ROWQ; u += 256) {
        const int x  = u >> 4;
        const int cq = u & 15;
        orow[u] = means[mrow + (size_t)scid[x] * 16 + cq];
    }
}

// ---- Fallback: R2 static wave-per-cell (only if ws too small) ----
__global__ __launch_bounds__(256) void cell_pool(const float4* __restrict__ in,
                                                 float4* __restrict__ out,
                                                 const int* __restrict__ ws) {
    const int nrows  = ws[OFF_NROWS];
    const int ncols  = ws[OFF_NCOLS];
    const int ncells = nrows * ncols;
    const int wave   = blockIdx.x * 4 + (threadIdx.x >> 6);
    const int nwaves = gridDim.x * 4;
    const int lane   = threadIdx.x & 63;
    const int pg     = lane >> 4;
    const int cq     = lane & 15;

    for (int cell = wave; cell < ncells; cell += nwaves) {
        const int br = cell / ncols;
        const int bc = cell - br * ncols;
        const int y0 = ws[OFF_ROWSTART + br];
        const int y1 = ws[OFF_ROWEND + br];
        const int x0 = ws[OFF_COLSTART + bc];
        const int x1 = ws[OFF_COLEND + bc];
        float4 a = make_float4(0.f,0.f,0.f,0.f);
        for (int y = y0; y < y1; ++y) {
            const size_t rb = (size_t)y * ROWQ + cq;
            for (int x = x0 + pg; x < x1; x += 4)
                acc4(a, in[rb + (size_t)x * 16]);
        }
        #pragma unroll
        for (int msk = 16; msk < 64; msk <<= 1) {
            a.x += __shfl_xor(a.x, msk, 64);
            a.y += __shfl_xor(a.y, msk, 64);
            a.z += __shfl_xor(a.z, msk, 64);
            a.w += __shfl_xor(a.w, msk, 64);
        }
        const float area = (float)((y1 - y0) * (x1 - x0));
        float4 mn = make_float4(a.x / area, a.y / area, a.z / area, a.w / area);
        for (int y = y0; y < y1; ++y) {
            const size_t rb = (size_t)y * ROWQ + cq;
            for (int x = x0 + pg; x < x1; x += 4)
                out[rb + (size_t)x * 16] = mn;
        }
    }
}

extern "C" void kernel_launch(void* const* d_in, const int* in_sizes, int n_in,
                              void* d_out, int out_size, void* d_ws, size_t ws_size,
                              hipStream_t stream) {
    const float* in  = (const float*)d_in[0];   // [1,768,768,64] fp32
    const int* hmask = (const int*)d_in[1];     // [1,768] int32
    const int* vmask = (const int*)d_in[2];     // [1,768] int32
    float* out = (float*)d_out;                 // [1,768,768,64] fp32
    int* ws = (int*)d_ws;

    seg_scan<<<2, GH, 0, stream>>>(hmask, vmask, ws);

    if (ws_size >= WS_NEED_BYTES) {
        float4* colsum = (float4*)((char*)d_ws + COLSUM_OFF_BYTES);
        float4* means  = (float4*)((char*)d_ws + MEANS_OFF_BYTES);
        col_sum<<<4096, 256, 0, stream>>>((const float4*)in, colsum, ws);
        cell_mean<<<2048, 256, 0, stream>>>(colsum, means, ws);
        bcast<<<GH, 256, 0, stream>>>(means, (float4*)out, ws);
    } else {
        cell_pool<<<2048, 256, 0, stream>>>((const float4*)in, (float4*)out, ws);
    }
}